// Round 4
// baseline (1542.005 us; speedup 1.0000x reference)
//
#include <hip/hip_runtime.h>
#include <math.h>

#define NBATCH 262144
#define INVSQH 0.08838834764831845f   // 1/sqrt(128)

typedef float f32x4 __attribute__((ext_vector_type(4)));
typedef short s16x8 __attribute__((ext_vector_type(8)));
typedef __bf16 bf16x2_t __attribute__((ext_vector_type(2)));

// ---- workspace layout (bytes) ----
// Wres bf16, fragment-major: 64 stages * 32768 B.
//   bf16 index = sidx*16384 + ((o>>4)*4 + (k>>5))*512 + (((k>>3)&3)*16 + (o&15))*8 + (k&7)
#define WSR_OFF 0
#define WSF_OFF 2097152           // Wf padded [32][128]: 16 * 8192 B, same fragment-major form
#define WS0_OFF 2228224           // W0 col0 packed: 16*128 f32
#define WSB_OFF 2236416           // proj bias padded: 16*32 f32
#define REC_OFF 2238464           // 16 * 40 f32 (cw9 ch9 d9 lu4 lub2)
#define LDC_OFF 2241024           // 1 f32: sum log-diag

#define P1S 28

__device__ __forceinline__ float softplusf(float x) {
    return (x > 15.f) ? x : log1pf(__expf(x));
}
__device__ __forceinline__ unsigned short f2bf(float x) {
    unsigned u = __float_as_uint(x);
    unsigned r = (u + 0x7FFFu + ((u >> 16) & 1u)) >> 16;   // RNE
    return (unsigned short)r;
}
// pack two fp32 -> bf16x2 dword, RNE. HW cvt_pk on gfx950 if available (bit-identical RNE).
__device__ __forceinline__ unsigned pack2bf(float a, float b) {
#if __has_builtin(__builtin_amdgcn_cvt_pk_bf16_f32)
    bf16x2_t r = __builtin_amdgcn_cvt_pk_bf16_f32(a, b);
    return __builtin_bit_cast(unsigned, r);
#else
    return (unsigned)f2bf(a) | ((unsigned)f2bf(b) << 16);
#endif
}

__device__ __forceinline__ void rqs_solve(float y, float yc, float yk, float hk, float xk,
                                          float wk, float dk, float dk1,
                                          float& xout, float& ldout)
{
    float sk = hk / wk;
    float dy = yc - yk;
    float t2 = dk + dk1 - 2.f * sk;
    float av = dy * t2 + hk * (sk - dk);
    float bv = hk * dk - dy * t2;
    float cv = -sk * dy;
    float disc = fmaxf(bv * bv - 4.f * av * cv, 0.f);
    float theta = 2.f * cv / (-bv - sqrtf(disc));
    float xo = fmaf(theta, wk, xk);
    float om = 1.f - theta;
    float denom = fmaf(t2, theta * om, sk);
    float dnum = sk * sk * (dk1 * theta * theta + 2.f * sk * theta * om + dk * om * om);
    float ldf = __logf(dnum) - 2.f * __logf(denom);
    bool inside = (y >= -3.f) && (y <= 3.f);
    xout  = inside ? xo : y;
    ldout = inside ? -ldf : 0.f;
}

// full RQS inverse from raw params p[0..22] (dim-1, per-sample)
__device__ __forceinline__ void rqs_inv(float y, const float* __restrict__ p,
                                        float& xout, float& ldout)
{
    float uw[8], uh[8];
#pragma unroll
    for (int j = 0; j < 8; ++j) uw[j] = p[j] * INVSQH;
#pragma unroll
    for (int j = 0; j < 8; ++j) uh[j] = p[8 + j] * INVSQH;
    float mw = uw[0], mh = uh[0];
#pragma unroll
    for (int j = 1; j < 8; ++j) { mw = fmaxf(mw, uw[j]); mh = fmaxf(mh, uh[j]); }
    float ew[8], eh[8], sw = 0.f, sh = 0.f;
#pragma unroll
    for (int j = 0; j < 8; ++j) {
        ew[j] = __expf(uw[j] - mw); sw += ew[j];
        eh[j] = __expf(uh[j] - mh); sh += eh[j];
    }
    float isw = 0.992f / sw, ish = 0.992f / sh;
    float cw[9], ch[9];
    cw[0] = -3.f; ch[0] = -3.f;
    float aw = 0.f, ah = 0.f;
#pragma unroll
    for (int j = 0; j < 8; ++j) {
        aw += 0.001f + ew[j] * isw;
        ah += 0.001f + eh[j] * ish;
        cw[j + 1] = 6.f * aw - 3.f;
        ch[j + 1] = 6.f * ah - 3.f;
    }
    cw[8] = 3.f; ch[8] = 3.f;
    float d[9];
    d[0] = 1.f; d[8] = 1.f;
#pragma unroll
    for (int j = 0; j < 7; ++j) d[j + 1] = 0.001f + softplusf(p[16 + j]);

    float yc = fminf(fmaxf(y, -3.f), 3.f);
    float yk = ch[0], hk = ch[1] - ch[0], xk = cw[0], wk = cw[1] - cw[0];
    float dk = d[0], dk1 = d[1];
#pragma unroll
    for (int j = 1; j < 8; ++j) {
        bool cge = (yc >= ch[j]);
        yk  = cge ? ch[j] : yk;
        hk  = cge ? (ch[j + 1] - ch[j]) : hk;
        xk  = cge ? cw[j] : xk;
        wk  = cge ? (cw[j + 1] - cw[j]) : wk;
        dk  = cge ? d[j] : dk;
        dk1 = cge ? d[j + 1] : dk1;
    }
    rqs_solve(y, yc, yk, hk, xk, wk, dk, dk1, xout, ldout);
}

// RQS inverse from precomputed knots rec = {cw[9], ch[9], d[9]} (dim-0, per-layer const)
__device__ __forceinline__ void rqs_knots(float y, const float* __restrict__ rec,
                                          float& xout, float& ldout)
{
    const float* cw = rec;
    const float* ch = rec + 9;
    const float* dd = rec + 18;
    float yc = fminf(fmaxf(y, -3.f), 3.f);
    float yk = ch[0], hk = ch[1] - ch[0], xk = cw[0], wk = cw[1] - cw[0];
    float dk = dd[0], dk1 = dd[1];
#pragma unroll
    for (int j = 1; j < 8; ++j) {
        bool cge = (yc >= ch[j]);
        yk  = cge ? ch[j] : yk;
        hk  = cge ? (ch[j + 1] - ch[j]) : hk;
        xk  = cge ? cw[j] : xk;
        wk  = cge ? (cw[j + 1] - cw[j]) : wk;
        dk  = cge ? dd[j] : dk;
        dk1 = cge ? dd[j + 1] : dk1;
    }
    rqs_solve(y, yc, yk, hk, xk, wk, dk, dk1, xout, ldout);
}

// packed bf16x4 store of one D-tile fragment into act buffer.
// element (m, k'=n) at byte m*256 + ((k'>>3)^(m&7))*16 + (k'&7)*2; lane's 4 k' consecutive.
__device__ __forceinline__ void pack_store(char* A, int m, int tn2, int i, int q, int tx7, f32x4 v)
{
    unsigned d0 = pack2bf(v[0], v[1]);
    unsigned d1 = pack2bf(v[2], v[3]);
    int chunk = ((tn2 << 3) + (i << 1) + (q >> 1)) ^ tx7;
    *(uint2*)(A + (m << 8) + (chunk << 4) + ((q & 1) << 3)) = make_uint2(d0, d1);
}

// One 128x128x128 transposed MFMA stage: out^T[n][m] = sum_k W[n][k] act[m][k].
// W-fragments come straight from global (L2-resident, fragment-major layout) — no LDS, no
// weight barriers. Wave w: tn2=w>>1 (n-half), tm2=w&1 (m-half).
// BSTAGE: acc init = h + bias, result is the new h. else acc init = bias (plain affine).
template <int BSTAGE, int RELUOUT>
__device__ __forceinline__ void res_stage(char* A, const char* Wg, const float* biasrow,
                                          f32x4 h[4][4],
                                          int tn2, int tm2, int q, int tx, int lane)
{
    const int tx7 = tx & 7;
    f32x4 acc[4][4];
#pragma unroll
    for (int i = 0; i < 4; ++i) {
        float4 bv = *(const float4*)(biasrow + tn2 * 64 + i * 16 + (q << 2));
        f32x4 bvv; bvv[0] = bv.x; bvv[1] = bv.y; bvv[2] = bv.z; bvv[3] = bv.w;
#pragma unroll
        for (int j = 0; j < 4; ++j)
            acc[i][j] = BSTAGE ? (h[i][j] + bvv) : bvv;
    }

#pragma unroll 1
    for (int ktg = 0; ktg < 4; ++ktg) {
        int ccA = ((ktg << 2) + q) ^ tx7;
        s16x8 wf[4], af[4];
#pragma unroll
        for (int i = 0; i < 4; ++i)
            wf[i] = *(const s16x8*)(Wg + ((((tn2 * 4 + i) * 4 + ktg) * 64 + lane) << 4));
#pragma unroll
        for (int j = 0; j < 4; ++j)
            af[j] = *(const s16x8*)(A + ((tm2 * 64 + j * 16 + tx) << 8) + (ccA << 4));
#pragma unroll
        for (int i = 0; i < 4; ++i)
#pragma unroll
            for (int j = 0; j < 4; ++j)
                acc[i][j] = __builtin_amdgcn_mfma_f32_16x16x32_bf16(wf[i], af[j], acc[i][j], 0, 0, 0);
    }
    __syncthreads();            // all A-reads complete before in-place overwrite

#pragma unroll
    for (int i = 0; i < 4; ++i)
#pragma unroll
        for (int j = 0; j < 4; ++j) {
            if (BSTAGE) h[i][j] = acc[i][j];
            f32x4 v = acc[i][j];
            if (RELUOUT) {
                v[0] = fmaxf(v[0], 0.f); v[1] = fmaxf(v[1], 0.f);
                v[2] = fmaxf(v[2], 0.f); v[3] = fmaxf(v[3], 0.f);
            }
            pack_store(A, tm2 * 64 + j * 16 + tx, tn2, i, q, tx7, v);
        }
    __syncthreads();            // writes visible to all waves
}

// ---------------- prep kernel ----------------
extern "C" __global__ void nsf_prep(const float* __restrict__ Wresg, const float* __restrict__ Wfg,
                                    const float* __restrict__ bfg, const float* __restrict__ W0g,
                                    const float* __restrict__ lulg, const float* __restrict__ luug,
                                    const float* __restrict__ ludg, const float* __restrict__ lubg,
                                    const int* __restrict__ permsg, char* __restrict__ ws)
{
    int t = blockIdx.x * blockDim.x + threadIdx.x;
    int stride = gridDim.x * blockDim.x;
    unsigned short* wr = (unsigned short*)(ws + WSR_OFF);
    unsigned short* wf = (unsigned short*)(ws + WSF_OFF);
    float* ws0 = (float*)(ws + WS0_OFF);
    float* wsb = (float*)(ws + WSB_OFF);

    // Wres fragment-major: sidx = L*4 + st (source linear order)
    for (int e = t; e < 16 * 4 * 16384; e += stride) {
        int sidx = e >> 14;
        int rem = e & 16383;
        int o = rem >> 7, k = rem & 127;
        wr[sidx * 16384 + ((o >> 4) * 4 + (k >> 5)) * 512
           + (((k >> 3) & 3) * 16 + (o & 15)) * 8 + (k & 7)] = f2bf(Wresg[e]);
    }
    // Wf padded to 32 rows, fragment-major per layer
    for (int e = t; e < 16 * 32 * 128; e += stride) {
        int L = e >> 12;
        int rem = e & 4095;
        int o = rem >> 7, k = rem & 127;
        float x = (o < 23) ? Wfg[(L * 46 + 23 + o) * 128 + k] : 0.f;
        wf[L * 4096 + ((o >> 4) * 4 + (k >> 5)) * 512
           + (((k >> 3) & 3) * 16 + (o & 15)) * 8 + (k & 7)] = f2bf(x);
    }
    // W0 column 0 packed; padded proj bias
    for (int e = t; e < 16 * 128; e += stride)
        ws0[e] = W0g[2 * e];
    for (int e = t; e < 16 * 32; e += stride) {
        int L = e >> 5, o = e & 31;
        wsb[e] = (o < 23) ? bfg[L * 46 + 23 + o] : 0.f;
    }
    // per-layer: dim0 spline knots + folded LU/perm
    if (t < 16) {
        int L = t;
        float* rec = (float*)(ws + REC_OFF) + L * 40;
        const float* p = bfg + L * 46;
        for (int half = 0; half < 2; ++half) {
            float u[8], m = -1e30f;
            for (int j = 0; j < 8; ++j) { u[j] = p[half * 8 + j] * INVSQH; m = fmaxf(m, u[j]); }
            float e[8], s = 0.f;
            for (int j = 0; j < 8; ++j) { e[j] = expf(u[j] - m); s += e[j]; }
            float cum = 0.f;
            rec[half * 9 + 0] = -3.f;
            for (int j = 0; j < 8; ++j) {
                cum += 0.001f + 0.992f * e[j] / s;
                rec[half * 9 + 1 + j] = 6.f * cum - 3.f;
            }
            rec[half * 9 + 8] = 3.f;
        }
        rec[18] = 1.f; rec[26] = 1.f;
        for (int j = 0; j < 7; ++j) {
            float x = p[16 + j];
            rec[19 + j] = 0.001f + ((x > 15.f) ? x : log1pf(expf(x)));
        }
        float x0 = ludg[2 * L], x1 = ludg[2 * L + 1];
        float dg0 = 0.001f + ((x0 > 15.f) ? x0 : log1pf(expf(x0)));
        float dg1 = 0.001f + ((x1 > 15.f) ? x1 : log1pf(expf(x1)));
        float ll = lulg[L], uu = luug[L];
        float det = dg0 * dg1;
        float c00 = (ll * uu + dg1) / det, c01 = -uu / det;
        float c10 = -ll / dg1, c11 = 1.f / dg1;
        int pa = permsg[2 * L], pb = permsg[2 * L + 1];
        rec[27] = pa ? c10 : c00; rec[28] = pa ? c11 : c01;
        rec[29] = pb ? c10 : c00; rec[30] = pb ? c11 : c01;
        rec[31] = lubg[2 * L];    rec[32] = lubg[2 * L + 1];
    }
    if (t == 16) {
        float s = 0.f;
        for (int L = 0; L < 16; ++L) {
            float x0 = ludg[2 * L], x1 = ludg[2 * L + 1];
            float dg0 = 0.001f + ((x0 > 15.f) ? x0 : log1pf(expf(x0)));
            float dg1 = 0.001f + ((x1 > 15.f) ? x1 : log1pf(expf(x1)));
            s += logf(dg0) + logf(dg1);
        }
        *(float*)(ws + LDC_OFF) = s;
    }
}

// ---------------- main fused kernel ----------------
extern "C" __global__ __launch_bounds__(256, 3)
void nsf_kernel(const float* __restrict__ z0g, const float* __restrict__ xg,
                const float* __restrict__ sgg,
                const float* __restrict__ n1w1, const float* __restrict__ n1b1,
                const float* __restrict__ n1w2, const float* __restrict__ n1b2,
                const float* __restrict__ n2w1, const float* __restrict__ n2b1,
                const float* __restrict__ n2w2, const float* __restrict__ n2b2,
                const float* __restrict__ b0g,  const float* __restrict__ bresg,
                const char* __restrict__ ws, float* __restrict__ outg)
{
    __shared__ char  A[128 * 256];          // activations bf16, swizzled 16B chunks
    __shared__ float out0sh[128];
    __shared__ float p1f[128 * P1S];

    const int tid = threadIdx.x;
    const int lane = tid & 63, w = tid >> 6;
    const int q = lane >> 4, tx = lane & 15, tx7 = tx & 7;
    const int tn2 = w >> 1, tm2 = w & 1;
    const int sbase = blockIdx.x * 128;

    const char* wsW = ws + WSR_OFF;
    const char* wsF = ws + WSF_OFF;
    const float* ws0 = (const float*)(ws + WS0_OFF);
    const float* wsb = (const float*)(ws + WSB_OFF);
    const float* recs = (const float*)(ws + REC_OFF);

    float zz0 = 0.f, zz1 = 0.f, ld = 0.f;
    if (tid < 128) {
        int s = sbase + tid;
        float za = z0g[2 * s], zb = z0g[2 * s + 1];
        float xa = xg[2 * s],  xb = xg[2 * s + 1];
        float sg = sgg[s];
        float t0 = n1b2[0], t1 = n1b2[1];
#pragma unroll
        for (int m = 0; m < 32; ++m) {
            float hm = fmaf(sg, n1w1[m], n1b1[m]);
            hm = hm / (1.f + __expf(-hm));
            t0 = fmaf(hm, n1w2[m], t0);
            t1 = fmaf(hm, n1w2[32 + m], t1);
        }
        float u0 = n2b2[0], u1 = n2b2[1];
#pragma unroll
        for (int m = 0; m < 32; ++m) {
            float hm = za * n2w1[4 * m] + zb * n2w1[4 * m + 1]
                     + xa * n2w1[4 * m + 2] + xb * n2w1[4 * m + 3] + n2b1[m];
            hm = hm / (1.f + __expf(-hm));
            u0 = fmaf(hm, n2w2[m], u0);
            u1 = fmaf(hm, n2w2[32 + m], u1);
        }
        zz0 = u0 + t0; zz1 = u1 + t1;
    }

    f32x4 h[4][4];

    for (int L = 0; L < 16; ++L) {
        const float* rec = recs + L * 40;
        float out0 = 0.f, ldp0 = 0.f;
        if (tid < 128) {
            rqs_knots(zz0, rec, out0, ldp0);
            out0sh[tid] = out0;
        }
        __syncthreads();                                   // out0sh visible (+ prev proj A-reads done)

        // ---- h init in registers + packed relu write into A ----
        {
#pragma unroll
            for (int i = 0; i < 4; ++i) {
                int n0 = tn2 * 64 + i * 16 + (q << 2);
                float4 w0v = *(const float4*)(ws0 + L * 128 + n0);
                float4 b0v = *(const float4*)(b0g + L * 128 + n0);
#pragma unroll
                for (int j = 0; j < 4; ++j) {
                    int m = tm2 * 64 + j * 16 + tx;
                    float o0 = out0sh[m];
                    f32x4 v;
                    v[0] = fmaf(o0, w0v.x, b0v.x);
                    v[1] = fmaf(o0, w0v.y, b0v.y);
                    v[2] = fmaf(o0, w0v.z, b0v.z);
                    v[3] = fmaf(o0, w0v.w, b0v.w);
                    h[i][j] = v;
                    v[0] = fmaxf(v[0], 0.f); v[1] = fmaxf(v[1], 0.f);
                    v[2] = fmaxf(v[2], 0.f); v[3] = fmaxf(v[3], 0.f);
                    pack_store(A, m, tn2, i, q, tx7, v);
                }
            }
        }
        __syncthreads();                                   // relu(h) visible

        const char* sw = wsW + L * 4 * 32768;
        const float* bb = bresg + L * 4 * 128;

        res_stage<0, 1>(A, sw + 0 * 32768, bb + 0,   h, tn2, tm2, q, tx, lane);  // t1
        res_stage<1, 1>(A, sw + 1 * 32768, bb + 128, h, tn2, tm2, q, tx, lane);  // h2 = h + ...
        res_stage<0, 1>(A, sw + 2 * 32768, bb + 256, h, tn2, tm2, q, tx, lane);  // t2
        res_stage<1, 0>(A, sw + 3 * 32768, bb + 384, h, tn2, tm2, q, tx, lane);  // h4 raw for proj

        // ---- projection: p1^T[o][m], Wf fragments from global, act in A ----
        {
            const char* fw = wsF + L * 8192;
            f32x4 pacc[2][2];
#pragma unroll
            for (int ct = 0; ct < 2; ++ct)
#pragma unroll
                for (int jm = 0; jm < 2; ++jm) pacc[ct][jm] = (f32x4){0.f, 0.f, 0.f, 0.f};
#pragma unroll
            for (int ktg = 0; ktg < 4; ++ktg) {
                int ccA = ((ktg << 2) + q) ^ tx7;
                s16x8 wfr[2], afr[2];
#pragma unroll
                for (int ct = 0; ct < 2; ++ct)
                    wfr[ct] = *(const s16x8*)(fw + (((ct * 4 + ktg) * 64 + lane) << 4));
#pragma unroll
                for (int jm = 0; jm < 2; ++jm)
                    afr[jm] = *(const s16x8*)(A + (((w << 5) + jm * 16 + tx) << 8) + (ccA << 4));
#pragma unroll
                for (int ct = 0; ct < 2; ++ct)
#pragma unroll
                    for (int jm = 0; jm < 2; ++jm)
                        pacc[ct][jm] = __builtin_amdgcn_mfma_f32_16x16x32_bf16(wfr[ct], afr[jm], pacc[ct][jm], 0, 0, 0);
            }
#pragma unroll
            for (int ct = 0; ct < 2; ++ct) {
                if (ct == 0 || q < 2) {
                    float4 bias = *(const float4*)(wsb + L * 32 + ct * 16 + (q << 2));
#pragma unroll
                    for (int jm = 0; jm < 2; ++jm) {
                        int m = (w << 5) + jm * 16 + tx;
                        float4 o;
                        o.x = pacc[ct][jm][0] + bias.x;
                        o.y = pacc[ct][jm][1] + bias.y;
                        o.z = pacc[ct][jm][2] + bias.z;
                        o.w = pacc[ct][jm][3] + bias.w;
                        *(float4*)(p1f + m * P1S + ct * 16 + (q << 2)) = o;
                    }
                }
            }
        }
        __syncthreads();                                   // p1 visible; A reads done

        // ---- dim-1 spline + folded LU/permute ----
        if (tid < 128) {
            float pp[24];
            const float4* pr = (const float4*)(p1f + tid * P1S);
#pragma unroll
            for (int i = 0; i < 6; ++i) {
                float4 v4 = pr[i];
                pp[4 * i] = v4.x; pp[4 * i + 1] = v4.y; pp[4 * i + 2] = v4.z; pp[4 * i + 3] = v4.w;
            }
            float out1, ldp1;
            rqs_inv(zz1, pp, out1, ldp1);
            ld += ldp0 + ldp1;
            float v0 = out0 - rec[31], v1 = out1 - rec[32];
            zz0 = fmaf(v0, rec[27], v1 * rec[28]);
            zz1 = fmaf(v0, rec[29], v1 * rec[30]);
        }
    }

    if (tid < 128) {
        int s = sbase + tid;
        float ldc = *(const float*)(ws + LDC_OFF);
        outg[2 * s] = zz0;
        outg[2 * s + 1] = zz1;
        outg[2 * NBATCH + s] = ld - ldc;
    }
}

extern "C" void kernel_launch(void* const* d_in, const int* in_sizes, int n_in,
                              void* d_out, int out_size, void* d_ws, size_t ws_size,
                              hipStream_t stream)
{
    const float* z0g  = (const float*)d_in[0];
    const float* xg   = (const float*)d_in[1];
    const float* sgg  = (const float*)d_in[2];
    const float* n1w1 = (const float*)d_in[3];
    const float* n1b1 = (const float*)d_in[4];
    const float* n1w2 = (const float*)d_in[5];
    const float* n1b2 = (const float*)d_in[6];
    const float* n2w1 = (const float*)d_in[7];
    const float* n2b1 = (const float*)d_in[8];
    const float* n2w2 = (const float*)d_in[9];
    const float* n2b2 = (const float*)d_in[10];
    const float* W0g  = (const float*)d_in[11];
    const float* b0g  = (const float*)d_in[12];
    const float* Wres = (const float*)d_in[13];
    const float* bres = (const float*)d_in[14];
    const float* Wfg  = (const float*)d_in[15];
    const float* bfg  = (const float*)d_in[16];
    const float* lul  = (const float*)d_in[17];
    const float* luu  = (const float*)d_in[18];
    const float* lud  = (const float*)d_in[19];
    const float* lub  = (const float*)d_in[20];
    const int*   perms= (const int*)d_in[21];
    float* outg = (float*)d_out;

    nsf_prep<<<1024, 256, 0, stream>>>(Wres, Wfg, bfg, W0g, lul, luu, lud, lub, perms, (char*)d_ws);
    nsf_kernel<<<NBATCH / 128, 256, 0, stream>>>(z0g, xg, sgg,
                                                 n1w1, n1b1, n1w2, n1b2,
                                                 n2w1, n2b1, n2w2, n2b2,
                                                 b0g, bres,
                                                 (const char*)d_ws, outg);
}